// Round 3
// baseline (748.322 us; speedup 1.0000x reference)
//
#include <hip/hip_runtime.h>
#include <hip/hip_bf16.h>

typedef __bf16 bf16x8 __attribute__((ext_vector_type(8)));
typedef float  f32x4  __attribute__((ext_vector_type(4)));

#define BSZ 8192

union BW2 { __bf16 b[2]; unsigned int u; };
union FR  { unsigned int u[4]; bf16x8 v; };

// ---------------- stats0 (9x9 second-moment) + weight prep merged ----------------
// prep: w1 -> w1b [64 oc][128 k], w2 -> w2b [128 oc][256 k], k = d*C + c
__global__ __launch_bounds__(256) void k_stats0(const float* __restrict__ x,
                                                float* __restrict__ part0,
                                                const float* __restrict__ w1,
                                                const float* __restrict__ w2,
                                                __bf16* __restrict__ w1b,
                                                __bf16* __restrict__ w2b) {
    __shared__ float sred[4 * 54];
    const int tid = threadIdx.x;
    {   // merged prep (first 128 blocks' thread-range)
        int t = blockIdx.x * 256 + tid;
        if (t < 8192) {           // w1: 64 oc x 128 k
            int oc = t >> 7, k = t & 127, c = k & 31, d = k >> 5;
            w1b[t] = (__bf16)w1[oc * 128 + c * 4 + d];
        }
        if (t < 32768) {          // w2: 128 oc x 256 k
            int oc = t >> 8, k = t & 255, c = k & 63, d = k >> 6;
            w2b[t] = (__bf16)w2[oc * 256 + c * 4 + d];
        }
    }
    float a[54];
#pragma unroll
    for (int i = 0; i < 54; i++) a[i] = 0.f;
    const int total = BSZ * 784;
    for (int p = blockIdx.x * 256 + tid; p < total; p += gridDim.x * 256) {
        int b = p / 784, pix = p - b * 784;
        int y = pix / 28, xx = pix - y * 28;
        const float* xb = x + (long)b * 784;
        float nv[9];
#pragma unroll
        for (int dy = 0; dy < 3; dy++) {
            int yy = y + dy - 1;
#pragma unroll
            for (int dx = 0; dx < 3; dx++) {
                int x2 = xx + dx - 1;
                nv[dy * 3 + dx] = (yy >= 0 && yy < 28 && x2 >= 0 && x2 < 28) ? xb[yy * 28 + x2] : 0.f;
            }
        }
        int idx = 0;
#pragma unroll
        for (int t2 = 0; t2 < 9; t2++) {
            float vt = nv[t2];
            a[45 + t2] += vt;
#pragma unroll
            for (int u = t2; u < 9; u++) { a[idx] += vt * nv[u]; idx++; }
        }
    }
#pragma unroll
    for (int i = 0; i < 54; i++) {
        float v = a[i];
        v += __shfl_xor(v, 1);  v += __shfl_xor(v, 2);  v += __shfl_xor(v, 4);
        v += __shfl_xor(v, 8);  v += __shfl_xor(v, 16); v += __shfl_xor(v, 32);
        a[i] = v;
    }
    const int l = tid & 63, w = tid >> 6;
    if (l == 0) {
#pragma unroll
        for (int i = 0; i < 54; i++) sred[w * 54 + i] = a[i];
    }
    __syncthreads();
    if (tid < 54)
        part0[blockIdx.x * 64 + tid] = sred[tid] + sred[54 + tid] + sred[108 + tid] + sred[162 + tid];
}

// finalize BN0; emit merged-pass conv0 B-fragments (bias folded into k-slots):
// B column n holds channels 2n+hh (hh = matrix 0/1). k = q*8 + e:
//   q<3 : e=2i+par (i<3): bf16(A*w[q*3+i]) for both parities (A supplies x_hi at e=2i, x_lo at 2i+1)
//         e=6: resid(q*3+0), e=7: resid(q*3+1)   (A supplies x_hi)
//   q==3: e=0: resid(2), e=1: resid(5), e=2: resid(8)  (A supplies x_hi of col-2 pixels)
//         e=4: bf16(bias), e=5: bias - bf16(bias)      (A supplies 1.0 at both)
__global__ void k_fin0(const float* __restrict__ part0, const float* __restrict__ w0,
                       const float* __restrict__ g0, const float* __restrict__ be0,
                       __bf16* __restrict__ wcv) {
    __shared__ float red[4 * 54];
    int t = threadIdx.x, c = t & 63, g = t >> 6;
    if (c < 54) {
        float acc = 0.f;
        for (int i = g; i < 1008; i += 4) acc += part0[i * 64 + c];
        red[g * 54 + c] = acc;
    }
    __syncthreads();
    if (t < 54) red[t] = red[t] + red[54 + t] + red[108 + t] + red[162 + t];
    __syncthreads();
    if (t < 32) {
        float wv[9];
#pragma unroll
        for (int tap = 0; tap < 9; tap++) wv[tap] = w0[t * 9 + tap];
        float sum = 0.f, sq = 0.f;
        int idx = 0;
#pragma unroll
        for (int ta = 0; ta < 9; ta++) {
            sum = fmaf(wv[ta], red[45 + ta], sum);
#pragma unroll
            for (int u = ta; u < 9; u++) {
                float coef = (u == ta) ? 1.f : 2.f;
                sq = fmaf(coef * wv[ta] * wv[u], red[idx], sq);
                idx++;
            }
        }
        float cnt = (float)BSZ * 784.f;
        float mean = sum / cnt;
        float var = sq / cnt - mean * mean;
        float A = g0[t] * rsqrtf(var + 1e-5f);
        float bias = be0[t] - mean * A;
        __bf16 bhi = (__bf16)bias;
        float blo = bias - (float)bhi;
        int nn = t >> 1, hh = t & 1;
#pragma unroll
        for (int qq = 0; qq < 4; qq++) {
#pragma unroll
            for (int e = 0; e < 8; e++) {
                float v = 0.f;
                if (qq < 3) {
                    if (e < 6) {
                        int i = e >> 1;
                        v = (float)((__bf16)(A * wv[qq * 3 + i]));
                    } else if (e == 6) {
                        float wf = A * wv[qq * 3 + 0]; v = wf - (float)((__bf16)wf);
                    } else {
                        float wf = A * wv[qq * 3 + 1]; v = wf - (float)((__bf16)wf);
                    }
                } else {
                    if (e == 0)      { float wf = A * wv[2]; v = wf - (float)((__bf16)wf); }
                    else if (e == 1) { float wf = A * wv[5]; v = wf - (float)((__bf16)wf); }
                    else if (e == 2) { float wf = A * wv[8]; v = wf - (float)((__bf16)wf); }
                    else if (e == 4) v = (float)bhi;
                    else if (e == 5) v = blo;
                }
                wcv[hh * 512 + qq * 128 + nn * 8 + e] = (__bf16)v;
            }
        }
    }
}

// ---------------- shared conv0/conv1 core pieces ----------------
struct C0S {
    bf16x8 bwM0, bwM1;
    int q, n;
    int Koff, off1, off2;
    bool q3;
};

__device__ inline void c0_init(C0S& S, const __bf16* __restrict__ wcv, int l) {
    S.q = l >> 4; S.n = l & 15; S.q3 = (S.q == 3);
    S.bwM0 = *(const bf16x8*)&wcv[S.q * 128 + S.n * 8];
    S.bwM1 = *(const bf16x8*)&wcv[512 + S.q * 128 + S.n * 8];
    S.Koff = S.q3 ? 2 : S.q * 30;
    S.off1 = S.q3 ? 30 : 1;
    S.off2 = S.q3 ? 60 : 2;
}

// produce one conv1 A-tile (16 positions x 128 k) into sAtw (stride 136), merged-pass conv0.
__device__ inline void c0_produce(const C0S& S, const unsigned* __restrict__ xs2w,
                                  __bf16* sAtw, int my, int mx, bool zpad) {
    const int b00 = 2 * my * 30 + 2 * mx + S.Koff;
#pragma unroll
    for (int t = 0; t < 4; t++) {
        const int d1 = t >> 1, d0 = t & 1;
        const unsigned* p = xs2w + b00 + d1 * 30 + d0;
        unsigned v0 = p[0], v1 = p[S.off1], v2 = p[S.off2];
        unsigned pm = __builtin_amdgcn_perm(v1, v0, 0x05040100u);   // (hi(v0), hi(v1))
        FR A;
        A.u[0] = S.q3 ? pm : v0;
        A.u[1] = S.q3 ? (v2 & 0xffffu) : v1;
        A.u[2] = S.q3 ? 0x3F803F80u : v2;     // q3: (1.0, 1.0) for bias hi/lo slots
        A.u[3] = S.q3 ? 0u : pm;
        f32x4 z = {0.f, 0.f, 0.f, 0.f};
        f32x4 ac0 = __builtin_amdgcn_mfma_f32_16x16x32_bf16(A.v, S.bwM0, z, 0, 0, 0);
        f32x4 ac1 = __builtin_amdgcn_mfma_f32_16x16x32_bf16(A.v, S.bwM1, z, 0, 0, 0);
#pragma unroll
        for (int r = 0; r < 4; r++) {
            float a0 = fmaxf(ac0[r], 0.f), a1 = fmaxf(ac1[r], 0.f);
            if (zpad) { a0 = 0.f; a1 = 0.f; }
            BW2 pk; pk.b[0] = (__bf16)a0; pk.b[1] = (__bf16)a1;
            *(unsigned*)&sAtw[(S.q * 4 + r) * 136 + t * 32 + 2 * S.n] = pk.u;
        }
    }
}

__device__ inline void stage_img(unsigned* xs2w, const float* __restrict__ x,
                                 long b, int t0, int stride) {
    for (int jj = t0; jj < 784; jj += stride) {
        int yy = jj / 28, xx2 = jj - yy * 28;
        float f = x[b * 784 + jj];
        __bf16 hi = (__bf16)f;
        __bf16 lo = (__bf16)(f - (float)hi);
        BW2 pk; pk.b[0] = hi; pk.b[1] = lo;
        xs2w[(yy + 1) * 30 + xx2 + 1] = pk.u;
    }
}

// ---------------- pass A: conv0+conv1 -> BN1 stats only (no stores), 1 wave = 1 image ----------------
__global__ __launch_bounds__(256, 4) void k_convA(const float* __restrict__ x,
                                                  const __bf16* __restrict__ wcv,
                                                  const __bf16* __restrict__ w1b,
                                                  float* __restrict__ part1) {
    __shared__ unsigned xs2a[4][900];
    __shared__ __attribute__((aligned(16))) __bf16 sAta[4][16 * 136];
    const int tid = threadIdx.x, w = tid >> 6, l = tid & 63;
    const int q = l >> 4, n = l & 15;
    unsigned* xs2w = xs2a[w];
    __bf16* sAtw = sAta[w];
    C0S S0; c0_init(S0, wcv, l);
    bf16x8 fbv[4][4];
#pragma unroll
    for (int g = 0; g < 4; g++)
#pragma unroll
        for (int kc = 0; kc < 4; kc++)
            fbv[g][kc] = *(const bf16x8*)&w1b[(4 * n + g) * 128 + kc * 32 + q * 8];
    const long b = (long)blockIdx.x * 4 + w;
    for (int i = l; i < 900; i += 64) xs2w[i] = 0u;
    stage_img(xs2w, x, b, l, 64);
    float ssum[4] = {0.f, 0.f, 0.f, 0.f}, ssq[4] = {0.f, 0.f, 0.f, 0.f};
    for (int mt = 0; mt < 13; mt++) {
        const bool last = (mt == 12);
        int mv = (last && n >= 4) ? 195 : mt * 16 + n;
        int my = mv / 14, mx = mv - my * 14;
        c0_produce(S0, xs2w, sAtw, my, mx, last && (q != 0));
        const __bf16* sa = &sAtw[n * 136 + q * 8];
        bf16x8 fav[4];
#pragma unroll
        for (int kc = 0; kc < 4; kc++) fav[kc] = *(const bf16x8*)&sa[kc * 32];
        __builtin_amdgcn_s_setprio(1);
#pragma unroll
        for (int g = 0; g < 4; g++) {
            f32x4 a = {0.f, 0.f, 0.f, 0.f};
#pragma unroll
            for (int kc = 0; kc < 4; kc++)
                a = __builtin_amdgcn_mfma_f32_16x16x32_bf16(fav[kc], fbv[g][kc], a, 0, 0, 0);
#pragma unroll
            for (int r = 0; r < 4; r++) {
                ssum[g] += a[r];                     // pad rows produce exact 0
                ssq[g] = fmaf(a[r], a[r], ssq[g]);
            }
        }
        __builtin_amdgcn_s_setprio(0);
    }
#pragma unroll
    for (int g = 0; g < 4; g++) {
        ssum[g] += __shfl_xor(ssum[g], 16); ssum[g] += __shfl_xor(ssum[g], 32);
        ssq[g]  += __shfl_xor(ssq[g], 16);  ssq[g]  += __shfl_xor(ssq[g], 32);
    }
    if (l < 16) {
#pragma unroll
        for (int g = 0; g < 4; g++) {
            part1[(long)(4 * l + g) * BSZ + b] = ssum[g];
            part1[(long)(64 + 4 * l + g) * BSZ + b] = ssq[g];
        }
    }
}

// ---------------- fused per-channel column reduce + BN finalize ----------------
__global__ __launch_bounds__(256) void k_redfin(const float* __restrict__ part,
                                                const float* __restrict__ g,
                                                const float* __restrict__ be,
                                                float* __restrict__ abc,
                                                int C, float cnt) {
    __shared__ float s1[256], s2[256];
    const int c = blockIdx.x, tid = threadIdx.x;
    float a = 0.f, bq = 0.f;
    const float* p1 = part + (long)c * BSZ;
    const float* p2 = part + (long)(C + c) * BSZ;
    for (int i = tid; i < BSZ; i += 256) { a += p1[i]; bq += p2[i]; }
    s1[tid] = a; s2[tid] = bq;
    __syncthreads();
    for (int s = 128; s > 0; s >>= 1) {
        if (tid < s) { s1[tid] += s1[tid + s]; s2[tid] += s2[tid + s]; }
        __syncthreads();
    }
    if (tid == 0) {
        float mean = s1[0] / cnt;
        float var = s2[0] / cnt - mean * mean;
        float A = g[c] * rsqrtf(var + 1e-5f);
        abc[c] = A;
        abc[C + c] = be[c] - mean * A;
    }
}

// ---------------- pass B: recompute conv0+conv1 -> h1 in LDS -> conv2 -> BN2 stats ----------------
// Block = 4 waves, one image at a time (4 images sequential). conv1: tiles split across waves
// (barrier-free within phase, per-wave sAt). conv2: cooperative, double-buffered sAt2 that
// aliases the per-wave sAt region (xs2 sits above it, never clobbered).
__global__ __launch_bounds__(256, 3) void k_convB(const float* __restrict__ x,
                                                  const __bf16* __restrict__ wcv,
                                                  const __bf16* __restrict__ w1b,
                                                  const __bf16* __restrict__ w2b,
                                                  const float* __restrict__ abc1,
                                                  float* __restrict__ part2) {
    __shared__ __attribute__((aligned(16))) unsigned char U[21008];
    __shared__ __attribute__((aligned(16))) __bf16 h1L[196 * 64];
    __shared__ float sbn1[128];
    const int tid = threadIdx.x, w = tid >> 6, l = tid & 63;
    const int q = l >> 4, n = l & 15;
    unsigned* xs2w = (unsigned*)(U + 17408);       // 900 dwords
    __bf16* sAtw = (__bf16*)(U + w * 4352);        // per-wave conv1 A-tile
    __bf16* sAt2 = (__bf16*)U;                     // conv2 A-tiles, 2 x 4224 bf16
    C0S S0; c0_init(S0, wcv, l);
    if (tid < 128) sbn1[tid] = abc1[tid];
    for (int i = tid; i < 900; i += 256) xs2w[i] = 0u;
    __syncthreads();

    for (int img = 0; img < 4; img++) {
        const long b = (long)blockIdx.x * 4 + img;
        stage_img(xs2w, x, b, tid, 256);
        __syncthreads();                           // xs2 ready; prev image fully consumed
        {   // ---- conv1: per-wave tile subset -> h1L ----
            bf16x8 fbv[4][4];
#pragma unroll
            for (int g = 0; g < 4; g++)
#pragma unroll
                for (int kc = 0; kc < 4; kc++)
                    fbv[g][kc] = *(const bf16x8*)&w1b[(4 * n + g) * 128 + kc * 32 + q * 8];
            for (int mt = w; mt < 13; mt += 4) {
                const bool last = (mt == 12);
                int mv = (last && n >= 4) ? 195 : mt * 16 + n;
                int my = mv / 14, mx = mv - my * 14;
                c0_produce(S0, xs2w, sAtw, my, mx, last && (q != 0));
                const __bf16* sa = &sAtw[n * 136 + q * 8];
                bf16x8 fav[4];
#pragma unroll
                for (int kc = 0; kc < 4; kc++) fav[kc] = *(const bf16x8*)&sa[kc * 32];
                const bool valid = (mt < 12) | (q == 0);
                __builtin_amdgcn_s_setprio(1);
#pragma unroll
                for (int g = 0; g < 4; g++) {
                    f32x4 a = {0.f, 0.f, 0.f, 0.f};
#pragma unroll
                    for (int kc = 0; kc < 4; kc++)
                        a = __builtin_amdgcn_mfma_f32_16x16x32_bf16(fav[kc], fbv[g][kc], a, 0, 0, 0);
                    if (valid) {
#pragma unroll
                        for (int r = 0; r < 4; r++)
                            h1L[(mt * 16 + q * 4 + r) * 64 + 4 * n + g] = (__bf16)a[r];
                    }
                }
                __builtin_amdgcn_s_setprio(0);
            }
        }
        __syncthreads();                           // h1L complete
        // ---- conv2 ----
        bf16x8 fbv2[2][8];
#pragma unroll
        for (int ntl = 0; ntl < 2; ntl++) {
            int oc = (2 * w + ntl) * 16 + n;
#pragma unroll
            for (int kc = 0; kc < 8; kc++)
                fbv2[ntl][kc] = *(const bf16x8*)&w2b[oc * 256 + kc * 32 + q * 8];
        }
        float s2a = 0.f, s2b = 0.f, q2a = 0.f, q2b = 0.f;
        for (int mt = 0; mt < 4; mt++) {
            __bf16* sb = sAt2 + (mt & 1) * 4224;
#pragma unroll
            for (int it = 0; it < 2; it++) {
                int idx = it * 256 + tid;
                int rl = idx >> 5, o = (idx & 31) * 8;
                int r = mt * 16 + rl;
                bf16x8 wv;
                if (r < 49) {
                    int d = o >> 6, c = o & 63;
                    int py = r / 7, px = r - py * 7;
                    int msrc = (2 * py + (d >> 1)) * 14 + 2 * px + (d & 1);
                    bf16x8 v = *(const bf16x8*)&h1L[msrc * 64 + c];
#pragma unroll
                    for (int j = 0; j < 8; j++)
                        wv[j] = (__bf16)fmaxf((float)v[j] * sbn1[c + j] + sbn1[64 + c + j], 0.f);
                } else {
#pragma unroll
                    for (int j = 0; j < 8; j++) wv[j] = (__bf16)0.0f;
                }
                *(bf16x8*)&sb[rl * 264 + o] = wv;
            }
            __syncthreads();                       // tile ready
            bf16x8 fav[8];
#pragma unroll
            for (int kc = 0; kc < 8; kc++)
                fav[kc] = *(const bf16x8*)&sb[n * 264 + kc * 32 + q * 8];
            f32x4 aA = {0.f, 0.f, 0.f, 0.f}, aB = {0.f, 0.f, 0.f, 0.f};
#pragma unroll
            for (int kc = 0; kc < 8; kc++) {
                aA = __builtin_amdgcn_mfma_f32_16x16x32_bf16(fav[kc], fbv2[0][kc], aA, 0, 0, 0);
                aB = __builtin_amdgcn_mfma_f32_16x16x32_bf16(fav[kc], fbv2[1][kc], aB, 0, 0, 0);
            }
#pragma unroll
            for (int rr = 0; rr < 4; rr++) {
                s2a += aA[rr]; q2a = fmaf(aA[rr], aA[rr], q2a);   // pad rows -> 0
                s2b += aB[rr]; q2b = fmaf(aB[rr], aB[rr], q2b);
            }
        }
        s2a += __shfl_xor(s2a, 16); s2a += __shfl_xor(s2a, 32);
        q2a += __shfl_xor(q2a, 16); q2a += __shfl_xor(q2a, 32);
        s2b += __shfl_xor(s2b, 16); s2b += __shfl_xor(s2b, 32);
        q2b += __shfl_xor(q2b, 16); q2b += __shfl_xor(q2b, 32);
        if (l < 16) {
            int oc0 = (2 * w + 0) * 16 + l, oc1 = (2 * w + 1) * 16 + l;
            part2[(long)oc0 * BSZ + b] = s2a;
            part2[(long)(128 + oc0) * BSZ + b] = q2a;
            part2[(long)oc1 * BSZ + b] = s2b;
            part2[(long)(128 + oc1) * BSZ + b] = q2b;
        }
    }
}

// ---------------- pass C: recompute all -> BN2+ReLU+avgpool+FC -> out ----------------
__global__ __launch_bounds__(256, 3) void k_convC(const float* __restrict__ x,
                                                  const __bf16* __restrict__ wcv,
                                                  const __bf16* __restrict__ w1b,
                                                  const __bf16* __restrict__ w2b,
                                                  const float* __restrict__ abc1,
                                                  const float* __restrict__ abc2,
                                                  const float* __restrict__ wfc,
                                                  const float* __restrict__ bfc,
                                                  float* __restrict__ out) {
    __shared__ __attribute__((aligned(16))) unsigned char U[21008];
    __shared__ __attribute__((aligned(16))) __bf16 h1L[196 * 64];
    __shared__ float sbn1[128];
    __shared__ float pooledL[128];
    __shared__ float fcred[80];
    const int tid = threadIdx.x, w = tid >> 6, l = tid & 63;
    const int q = l >> 4, n = l & 15;
    unsigned* xs2w = (unsigned*)(U + 17408);
    __bf16* sAtw = (__bf16*)(U + w * 4352);
    __bf16* sAt2 = (__bf16*)U;
    C0S S0; c0_init(S0, wcv, l);
    if (tid < 128) sbn1[tid] = abc1[tid];
    const float a20 = abc2[(2 * w + 0) * 16 + n], b20 = abc2[128 + (2 * w + 0) * 16 + n];
    const float a21 = abc2[(2 * w + 1) * 16 + n], b21 = abc2[128 + (2 * w + 1) * 16 + n];
    for (int i = tid; i < 900; i += 256) xs2w[i] = 0u;
    __syncthreads();

    for (int img = 0; img < 4; img++) {
        const long b = (long)blockIdx.x * 4 + img;
        stage_img(xs2w, x, b, tid, 256);
        __syncthreads();
        {   // conv1 -> h1L
            bf16x8 fbv[4][4];
#pragma unroll
            for (int g = 0; g < 4; g++)
#pragma unroll
                for (int kc = 0; kc < 4; kc++)
                    fbv[g][kc] = *(const bf16x8*)&w1b[(4 * n + g) * 128 + kc * 32 + q * 8];
            for (int mt = w; mt < 13; mt += 4) {
                const bool last = (mt == 12);
                int mv = (last && n >= 4) ? 195 : mt * 16 + n;
                int my = mv / 14, mx = mv - my * 14;
                c0_produce(S0, xs2w, sAtw, my, mx, last && (q != 0));
                const __bf16* sa = &sAtw[n * 136 + q * 8];
                bf16x8 fav[4];
#pragma unroll
                for (int kc = 0; kc < 4; kc++) fav[kc] = *(const bf16x8*)&sa[kc * 32];
                const bool valid = (mt < 12) | (q == 0);
                __builtin_amdgcn_s_setprio(1);
#pragma unroll
                for (int g = 0; g < 4; g++) {
                    f32x4 a = {0.f, 0.f, 0.f, 0.f};
#pragma unroll
                    for (int kc = 0; kc < 4; kc++)
                        a = __builtin_amdgcn_mfma_f32_16x16x32_bf16(fav[kc], fbv[g][kc], a, 0, 0, 0);
                    if (valid) {
#pragma unroll
                        for (int r = 0; r < 4; r++)
                            h1L[(mt * 16 + q * 4 + r) * 64 + 4 * n + g] = (__bf16)a[r];
                    }
                }
                __builtin_amdgcn_s_setprio(0);
            }
        }
        __syncthreads();
        // ---- conv2 + BN2+ReLU pooling ----
        bf16x8 fbv2[2][8];
#pragma unroll
        for (int ntl = 0; ntl < 2; ntl++) {
            int oc = (2 * w + ntl) * 16 + n;
#pragma unroll
            for (int kc = 0; kc < 8; kc++)
                fbv2[ntl][kc] = *(const bf16x8*)&w2b[oc * 256 + kc * 32 + q * 8];
        }
        float pl0 = 0.f, pl1 = 0.f;
        for (int mt = 0; mt < 4; mt++) {
            __bf16* sb = sAt2 + (mt & 1) * 4224;
#pragma unroll
            for (int it = 0; it < 2; it++) {
                int idx = it * 256 + tid;
                int rl = idx >> 5, o = (idx & 31) * 8;
                int r = mt * 16 + rl;
                bf16x8 wv;
                if (r < 49) {
                    int d = o >> 6, c = o & 63;
                    int py = r / 7, px = r - py * 7;
                    int msrc = (2 * py + (d >> 1)) * 14 + 2 * px + (d & 1);
                    bf16x8 v = *(const bf16x8*)&h1L[msrc * 64 + c];
#pragma unroll
                    for (int j = 0; j < 8; j++)
                        wv[j] = (__bf16)fmaxf((float)v[j] * sbn1[c + j] + sbn1[64 + c + j], 0.f);
                } else {
#pragma unroll
                    for (int j = 0; j < 8; j++) wv[j] = (__bf16)0.0f;
                }
                *(bf16x8*)&sb[rl * 264 + o] = wv;
            }
            __syncthreads();
            bf16x8 fav[8];
#pragma unroll
            for (int kc = 0; kc < 8; kc++)
                fav[kc] = *(const bf16x8*)&sb[n * 264 + kc * 32 + q * 8];
            f32x4 aA = {0.f, 0.f, 0.f, 0.f}, aB = {0.f, 0.f, 0.f, 0.f};
#pragma unroll
            for (int kc = 0; kc < 8; kc++) {
                aA = __builtin_amdgcn_mfma_f32_16x16x32_bf16(fav[kc], fbv2[0][kc], aA, 0, 0, 0);
                aB = __builtin_amdgcn_mfma_f32_16x16x32_bf16(fav[kc], fbv2[1][kc], aB, 0, 0, 0);
            }
#pragma unroll
            for (int rr = 0; rr < 4; rr++) {
                int pos = mt * 16 + q * 4 + rr;
                if (pos < 49) {
                    pl0 += fmaxf((float)(__bf16)aA[rr] * a20 + b20, 0.f);
                    pl1 += fmaxf((float)(__bf16)aB[rr] * a21 + b21, 0.f);
                }
            }
        }
        pl0 += __shfl_xor(pl0, 16); pl0 += __shfl_xor(pl0, 32);
        pl1 += __shfl_xor(pl1, 16); pl1 += __shfl_xor(pl1, 32);
        if (l < 16) {
            pooledL[(2 * w + 0) * 16 + l] = pl0 * (1.f / 49.f);
            pooledL[(2 * w + 1) * 16 + l] = pl1 * (1.f / 49.f);
        }
        __syncthreads();
        if (tid < 80) {
            int o = tid >> 3, s = tid & 7;
            float a = 0.f;
#pragma unroll
            for (int j = 0; j < 16; j++)
                a = fmaf(pooledL[s * 16 + j], wfc[o * 128 + s * 16 + j], a);
            fcred[tid] = a;
        }
        __syncthreads();
        if (tid < 10) {
            float a = bfc[tid];
#pragma unroll
            for (int s = 0; s < 8; s++) a += fcred[tid * 8 + s];
            out[b * 10 + tid] = a;
        }
    }
}

extern "C" void kernel_launch(void* const* d_in, const int* in_sizes, int n_in,
                              void* d_out, int out_size, void* d_ws, size_t ws_size,
                              hipStream_t stream) {
    const float* x   = (const float*)d_in[0];
    const float* w0  = (const float*)d_in[1];
    const float* g0  = (const float*)d_in[3];
    const float* be0 = (const float*)d_in[4];
    const float* w1  = (const float*)d_in[5];
    const float* g1  = (const float*)d_in[7];
    const float* be1 = (const float*)d_in[8];
    const float* w2  = (const float*)d_in[9];
    const float* g2  = (const float*)d_in[11];
    const float* be2 = (const float*)d_in[12];
    const float* wfc = (const float*)d_in[13];
    const float* bfc = (const float*)d_in[14];
    float* out = (float*)d_out;

    float* ws    = (float*)d_ws;
    float* part0 = ws;                            // 1008*64 used; tail holds wcv
    __bf16* wcv  = (__bf16*)(part0 + 1008 * 64);  // 2048 bf16
    float* abc0  = part0 + 1024 * 64;             // (unused hole, layout compat)
    float* part1 = abc0 + 320;                    // 128*8192
    float* abc1  = part1 + 128 * BSZ;             // 128
    float* part2 = abc1 + 128;                    // 256*8192
    float* abc2  = part2 + 256 * BSZ;             // 256
    __bf16* w1b  = (__bf16*)(abc2 + 256);         // 8192
    __bf16* w2b  = w1b + 8192;                    // 32768

    k_stats0<<<dim3(1008), dim3(256), 0, stream>>>(x, part0, w1, w2, w1b, w2b);
    k_fin0<<<dim3(1), dim3(256), 0, stream>>>(part0, w0, g0, be0, wcv);
    k_convA<<<dim3(BSZ / 4), dim3(256), 0, stream>>>(x, wcv, w1b, part1);
    k_redfin<<<dim3(64), dim3(256), 0, stream>>>(part1, g1, be1, abc1, 64, (float)(BSZ * 196));
    k_convB<<<dim3(BSZ / 4), dim3(256), 0, stream>>>(x, wcv, w1b, w2b, abc1, part2);
    k_redfin<<<dim3(128), dim3(256), 0, stream>>>(part2, g2, be2, abc2, 128, (float)(BSZ * 49));
    k_convC<<<dim3(BSZ / 4), dim3(256), 0, stream>>>(x, wcv, w1b, w2b, abc1, abc2, wfc, bfc, out);
}

// Round 4
// 368.529 us; speedup vs baseline: 2.0306x; 2.0306x over previous
//
#include <hip/hip_runtime.h>
#include <hip/hip_bf16.h>

typedef __bf16 bf16x8 __attribute__((ext_vector_type(8)));
typedef float  f32x4  __attribute__((ext_vector_type(4)));

#define BSZ 8192

union BW2 { __bf16 b[2]; unsigned int u; };
union FR  { unsigned int u[4]; bf16x8 v; };

// ---------------- stats0 (9x9 second-moment) + weight prep merged ----------------
// prep: w1 -> w1b [64 oc][128 k], w2 -> w2b [128 oc][256 k], k = d*C + c
__global__ __launch_bounds__(256) void k_stats0(const float* __restrict__ x,
                                                float* __restrict__ part0,
                                                const float* __restrict__ w1,
                                                const float* __restrict__ w2,
                                                __bf16* __restrict__ w1b,
                                                __bf16* __restrict__ w2b) {
    __shared__ float sred[4 * 54];
    const int tid = threadIdx.x;
    {   // merged prep (first 128 blocks' thread-range)
        int t = blockIdx.x * 256 + tid;
        if (t < 8192) {           // w1: 64 oc x 128 k
            int oc = t >> 7, k = t & 127, c = k & 31, d = k >> 5;
            w1b[t] = (__bf16)w1[oc * 128 + c * 4 + d];
        }
        if (t < 32768) {          // w2: 128 oc x 256 k
            int oc = t >> 8, k = t & 255, c = k & 63, d = k >> 6;
            w2b[t] = (__bf16)w2[oc * 256 + c * 4 + d];
        }
    }
    float a[54];
#pragma unroll
    for (int i = 0; i < 54; i++) a[i] = 0.f;
    const int total = BSZ * 784;
    for (int p = blockIdx.x * 256 + tid; p < total; p += gridDim.x * 256) {
        int b = p / 784, pix = p - b * 784;
        int y = pix / 28, xx = pix - y * 28;
        const float* xb = x + (long)b * 784;
        float nv[9];
#pragma unroll
        for (int dy = 0; dy < 3; dy++) {
            int yy = y + dy - 1;
#pragma unroll
            for (int dx = 0; dx < 3; dx++) {
                int x2 = xx + dx - 1;
                nv[dy * 3 + dx] = (yy >= 0 && yy < 28 && x2 >= 0 && x2 < 28) ? xb[yy * 28 + x2] : 0.f;
            }
        }
        int idx = 0;
#pragma unroll
        for (int t2 = 0; t2 < 9; t2++) {
            float vt = nv[t2];
            a[45 + t2] += vt;
#pragma unroll
            for (int u = t2; u < 9; u++) { a[idx] += vt * nv[u]; idx++; }
        }
    }
#pragma unroll
    for (int i = 0; i < 54; i++) {
        float v = a[i];
        v += __shfl_xor(v, 1);  v += __shfl_xor(v, 2);  v += __shfl_xor(v, 4);
        v += __shfl_xor(v, 8);  v += __shfl_xor(v, 16); v += __shfl_xor(v, 32);
        a[i] = v;
    }
    const int l = tid & 63, w = tid >> 6;
    if (l == 0) {
#pragma unroll
        for (int i = 0; i < 54; i++) sred[w * 54 + i] = a[i];
    }
    __syncthreads();
    if (tid < 54)
        part0[blockIdx.x * 64 + tid] = sred[tid] + sred[54 + tid] + sred[108 + tid] + sred[162 + tid];
}

// finalize BN0; emit merged-pass conv0 B-fragments (bias folded into k-slots):
// B column n holds channels 2n+hh (hh = matrix 0/1). k = q*8 + e:
//   q<3 : e=2i+par (i<3): bf16(A*w[q*3+i]) for both parities (A supplies x_hi at e=2i, x_lo at 2i+1)
//         e=6: resid(q*3+0), e=7: resid(q*3+1)   (A supplies x_hi)
//   q==3: e=0: resid(2), e=1: resid(5), e=2: resid(8)  (A supplies x_hi of col-2 pixels)
//         e=4: bf16(bias), e=5: bias - bf16(bias)      (A supplies 1.0 at both)
__global__ void k_fin0(const float* __restrict__ part0, const float* __restrict__ w0,
                       const float* __restrict__ g0, const float* __restrict__ be0,
                       __bf16* __restrict__ wcv) {
    __shared__ float red[4 * 54];
    int t = threadIdx.x, c = t & 63, g = t >> 6;
    if (c < 54) {
        float acc = 0.f;
        for (int i = g; i < 1008; i += 4) acc += part0[i * 64 + c];
        red[g * 54 + c] = acc;
    }
    __syncthreads();
    if (t < 54) red[t] = red[t] + red[54 + t] + red[108 + t] + red[162 + t];
    __syncthreads();
    if (t < 32) {
        float wv[9];
#pragma unroll
        for (int tap = 0; tap < 9; tap++) wv[tap] = w0[t * 9 + tap];
        float sum = 0.f, sq = 0.f;
        int idx = 0;
#pragma unroll
        for (int ta = 0; ta < 9; ta++) {
            sum = fmaf(wv[ta], red[45 + ta], sum);
#pragma unroll
            for (int u = ta; u < 9; u++) {
                float coef = (u == ta) ? 1.f : 2.f;
                sq = fmaf(coef * wv[ta] * wv[u], red[idx], sq);
                idx++;
            }
        }
        float cnt = (float)BSZ * 784.f;
        float mean = sum / cnt;
        float var = sq / cnt - mean * mean;
        float A = g0[t] * rsqrtf(var + 1e-5f);
        float bias = be0[t] - mean * A;
        __bf16 bhi = (__bf16)bias;
        float blo = bias - (float)bhi;
        int nn = t >> 1, hh = t & 1;
#pragma unroll
        for (int qq = 0; qq < 4; qq++) {
#pragma unroll
            for (int e = 0; e < 8; e++) {
                float v = 0.f;
                if (qq < 3) {
                    if (e < 6) {
                        int i = e >> 1;
                        v = (float)((__bf16)(A * wv[qq * 3 + i]));
                    } else if (e == 6) {
                        float wf = A * wv[qq * 3 + 0]; v = wf - (float)((__bf16)wf);
                    } else {
                        float wf = A * wv[qq * 3 + 1]; v = wf - (float)((__bf16)wf);
                    }
                } else {
                    if (e == 0)      { float wf = A * wv[2]; v = wf - (float)((__bf16)wf); }
                    else if (e == 1) { float wf = A * wv[5]; v = wf - (float)((__bf16)wf); }
                    else if (e == 2) { float wf = A * wv[8]; v = wf - (float)((__bf16)wf); }
                    else if (e == 4) v = (float)bhi;
                    else if (e == 5) v = blo;
                }
                wcv[hh * 512 + qq * 128 + nn * 8 + e] = (__bf16)v;
            }
        }
    }
}

// ---------------- shared conv0 core pieces ----------------
struct C0S {
    bf16x8 bwM0, bwM1;
    int q, n;
    int Koff, off1, off2;
    bool q3;
};

__device__ inline void c0_init(C0S& S, const __bf16* __restrict__ wcv, int l) {
    S.q = l >> 4; S.n = l & 15; S.q3 = (S.q == 3);
    S.bwM0 = *(const bf16x8*)&wcv[S.q * 128 + S.n * 8];
    S.bwM1 = *(const bf16x8*)&wcv[512 + S.q * 128 + S.n * 8];
    S.Koff = S.q3 ? 2 : S.q * 30;
    S.off1 = S.q3 ? 30 : 1;
    S.off2 = S.q3 ? 60 : 2;
}

// produce one conv1 A-tile (16 positions x 128 k) into sAtw (stride 136), merged-pass conv0.
__device__ inline void c0_produce(const C0S& S, const unsigned* __restrict__ xs2w,
                                  __bf16* sAtw, int my, int mx, bool zpad) {
    const int b00 = 2 * my * 30 + 2 * mx + S.Koff;
#pragma unroll
    for (int t = 0; t < 4; t++) {
        const int d1 = t >> 1, d0 = t & 1;
        const unsigned* p = xs2w + b00 + d1 * 30 + d0;
        unsigned v0 = p[0], v1 = p[S.off1], v2 = p[S.off2];
        unsigned pm = __builtin_amdgcn_perm(v1, v0, 0x05040100u);   // (hi(v0), hi(v1))
        FR A;
        A.u[0] = S.q3 ? pm : v0;
        A.u[1] = S.q3 ? (v2 & 0xffffu) : v1;
        A.u[2] = S.q3 ? 0x3F803F80u : v2;     // q3: (1.0, 1.0) for bias hi/lo slots
        A.u[3] = S.q3 ? 0u : pm;
        f32x4 z = {0.f, 0.f, 0.f, 0.f};
        f32x4 ac0 = __builtin_amdgcn_mfma_f32_16x16x32_bf16(A.v, S.bwM0, z, 0, 0, 0);
        f32x4 ac1 = __builtin_amdgcn_mfma_f32_16x16x32_bf16(A.v, S.bwM1, z, 0, 0, 0);
#pragma unroll
        for (int r = 0; r < 4; r++) {
            float a0 = fmaxf(ac0[r], 0.f), a1 = fmaxf(ac1[r], 0.f);
            if (zpad) { a0 = 0.f; a1 = 0.f; }
            BW2 pk; pk.b[0] = (__bf16)a0; pk.b[1] = (__bf16)a1;
            *(unsigned*)&sAtw[(S.q * 4 + r) * 136 + t * 32 + 2 * S.n] = pk.u;
        }
    }
}

__device__ inline void stage_img(unsigned* xs2w, const float* __restrict__ x,
                                 long b, int t0, int stride) {
    for (int jj = t0; jj < 784; jj += stride) {
        int yy = jj / 28, xx2 = jj - yy * 28;
        float f = x[b * 784 + jj];
        __bf16 hi = (__bf16)f;
        __bf16 lo = (__bf16)(f - (float)hi);
        BW2 pk; pk.b[0] = hi; pk.b[1] = lo;
        xs2w[(yy + 1) * 30 + xx2 + 1] = pk.u;
    }
}

// ---------------- conv0 (merged-pass MFMA) + conv1 (MFMA) -> h1 + BN1 stats ----------------
// 4 independent waves per block, 1 wave = 1 image, barrier-free (per-wave LDS, in-order DS pipe).
// oc remap 4n+g => per-row 8B packed h1 stores (4 per tile vs 16 scalar).
__global__ __launch_bounds__(256, 4) void k_conv01(const float* __restrict__ x,
                                                   const __bf16* __restrict__ wcv,
                                                   const __bf16* __restrict__ w1b,
                                                   __bf16* __restrict__ h1,
                                                   float* __restrict__ part1) {
    __shared__ unsigned xs2a[4][900];
    __shared__ __attribute__((aligned(16))) __bf16 sAta[4][16 * 136];
    const int tid = threadIdx.x, w = tid >> 6, l = tid & 63;
    const int q = l >> 4, n = l & 15;
    unsigned* xs2w = xs2a[w];
    __bf16* sAtw = sAta[w];
    C0S S0; c0_init(S0, wcv, l);
    bf16x8 fbv[4][4];
#pragma unroll
    for (int g = 0; g < 4; g++)
#pragma unroll
        for (int kc = 0; kc < 4; kc++)
            fbv[g][kc] = *(const bf16x8*)&w1b[(4 * n + g) * 128 + kc * 32 + q * 8];
    const long b = (long)blockIdx.x * 4 + w;
    for (int i = l; i < 900; i += 64) xs2w[i] = 0u;
    stage_img(xs2w, x, b, l, 64);
    float ssum[4] = {0.f, 0.f, 0.f, 0.f}, ssq[4] = {0.f, 0.f, 0.f, 0.f};
    __bf16* hb = h1 + b * 12544;
    for (int mt = 0; mt < 13; mt++) {
        const bool last = (mt == 12);
        int mv = (last && n >= 4) ? 195 : mt * 16 + n;
        int my = mv / 14, mx = mv - my * 14;
        c0_produce(S0, xs2w, sAtw, my, mx, last && (q != 0));
        const __bf16* sa = &sAtw[n * 136 + q * 8];
        bf16x8 fav[4];
#pragma unroll
        for (int kc = 0; kc < 4; kc++) fav[kc] = *(const bf16x8*)&sa[kc * 32];
        f32x4 a[4];
        __builtin_amdgcn_s_setprio(1);
#pragma unroll
        for (int g = 0; g < 4; g++) {
            f32x4 acc = {0.f, 0.f, 0.f, 0.f};
#pragma unroll
            for (int kc = 0; kc < 4; kc++)
                acc = __builtin_amdgcn_mfma_f32_16x16x32_bf16(fav[kc], fbv[g][kc], acc, 0, 0, 0);
            a[g] = acc;
        }
        __builtin_amdgcn_s_setprio(0);
#pragma unroll
        for (int g = 0; g < 4; g++)
#pragma unroll
            for (int r = 0; r < 4; r++) {
                ssum[g] += a[g][r];                  // pad rows produce exact 0
                ssq[g] = fmaf(a[g][r], a[g][r], ssq[g]);
            }
        if ((mt < 12) | (q == 0)) {
#pragma unroll
            for (int r = 0; r < 4; r++) {
                BW2 p0, p1;
                p0.b[0] = (__bf16)a[0][r]; p0.b[1] = (__bf16)a[1][r];
                p1.b[0] = (__bf16)a[2][r]; p1.b[1] = (__bf16)a[3][r];
                uint2 u; u.x = p0.u; u.y = p1.u;
                *(uint2*)&hb[(mt * 16 + q * 4 + r) * 64 + 4 * n] = u;
            }
        }
    }
#pragma unroll
    for (int g = 0; g < 4; g++) {
        ssum[g] += __shfl_xor(ssum[g], 16); ssum[g] += __shfl_xor(ssum[g], 32);
        ssq[g]  += __shfl_xor(ssq[g], 16);  ssq[g]  += __shfl_xor(ssq[g], 32);
    }
    if (l < 16) {
#pragma unroll
        for (int g = 0; g < 4; g++) {
            part1[(long)(4 * l + g) * BSZ + b] = ssum[g];
            part1[(long)(64 + 4 * l + g) * BSZ + b] = ssq[g];
        }
    }
}

// ---------------- fused per-channel column reduce + BN finalize ----------------
__global__ __launch_bounds__(256) void k_redfin(const float* __restrict__ part,
                                                const float* __restrict__ g,
                                                const float* __restrict__ be,
                                                float* __restrict__ abc,
                                                int C, float cnt) {
    __shared__ float s1[256], s2[256];
    const int c = blockIdx.x, tid = threadIdx.x;
    float a = 0.f, bq = 0.f;
    const float* p1 = part + (long)c * BSZ;
    const float* p2 = part + (long)(C + c) * BSZ;
    for (int i = tid; i < BSZ; i += 256) { a += p1[i]; bq += p2[i]; }
    s1[tid] = a; s2[tid] = bq;
    __syncthreads();
    for (int s = 128; s > 0; s >>= 1) {
        if (tid < s) { s1[tid] += s1[tid + s]; s2[tid] += s2[tid + s]; }
        __syncthreads();
    }
    if (tid == 0) {
        float mean = s1[0] / cnt;
        float var = s2[0] / cnt - mean * mean;
        float A = g[c] * rsqrtf(var + 1e-5f);
        abc[c] = A;
        abc[C + c] = be[c] - mean * A;
    }
}

// ---------------- conv2 MFMA (BN1+ReLU on load), streamed tiles, 4 images/block ----------------
// oc remap: oc = w*32 + 2n + ntl => a lane's two accumulators are ADJACENT channels ->
// packed dword zt writes. Stats on f32 accumulators directly. z2 stores via zt bounce.
// alias safety per tile mt: z2 writes at elem < (mt+1)*2048; produce(mt+1) loads at elem >= 3584/7168/10752.
__global__ __launch_bounds__(256) void k_conv2s(__bf16* __restrict__ h1,
                                                const __bf16* __restrict__ w2b,
                                                const float* __restrict__ abc1,
                                                float* __restrict__ part2) {
    __shared__ __attribute__((aligned(16))) __bf16 sAt[2][16 * 264];
    __shared__ __attribute__((aligned(16))) __bf16 zt[16 * 136];
    __shared__ float sbn1[128];
    const int tid = threadIdx.x;
    if (tid < 128) sbn1[tid] = abc1[tid];
    const int w = tid >> 6, l = tid & 63, q = l >> 4, n = l & 15;
    bf16x8 fbv[2][8];
#pragma unroll
    for (int ntl = 0; ntl < 2; ntl++) {
        int oc = w * 32 + 2 * n + ntl;
#pragma unroll
        for (int kc = 0; kc < 8; kc++)
            fbv[ntl][kc] = *(const bf16x8*)&w2b[oc * 256 + kc * 32 + q * 8];
    }
    __syncthreads();   // sbn1 ready

    for (int img = 0; img < 4; img++) {
        const int b = blockIdx.x * 4 + img;
        __bf16* src = h1 + (long)b * 12544;
        float ssum[2] = {0.f, 0.f}, ssq[2] = {0.f, 0.f};
        for (int mt = 0; mt < 4; mt++) {
            // ---- produce tile mt into sAt[mt&1]: 512 chunks, 2 per thread ----
#pragma unroll
            for (int it = 0; it < 2; it++) {
                int idx = it * 256 + tid;
                int rl = idx >> 5, o = (idx & 31) * 8;
                int r = mt * 16 + rl;
                bf16x8 wv;
                if (r < 49) {
                    int d = o >> 6, c = o & 63;
                    int py = r / 7, px = r - py * 7;
                    int msrc = (2 * py + (d >> 1)) * 14 + 2 * px + (d & 1);
                    bf16x8 v = *(const bf16x8*)&src[msrc * 64 + c];
#pragma unroll
                    for (int j = 0; j < 8; j++) {
                        float f = fmaxf((float)v[j] * sbn1[c + j] + sbn1[64 + c + j], 0.f);
                        wv[j] = (__bf16)f;
                    }
                } else {
#pragma unroll
                    for (int j = 0; j < 8; j++) wv[j] = (__bf16)0.0f;
                }
                *(bf16x8*)&sAt[mt & 1][rl * 264 + o] = wv;
            }
            __syncthreads();   // B1: tile ready (also: all prior zt reads precede this in program order)
            // ---- consume tile mt: MFMA -> zt (packed pairs) + f32 stats ----
            bf16x8 fav[8];
#pragma unroll
            for (int kc = 0; kc < 8; kc++)
                fav[kc] = *(const bf16x8*)&sAt[mt & 1][n * 264 + kc * 32 + q * 8];
            f32x4 accA = {0.f, 0.f, 0.f, 0.f}, accB = {0.f, 0.f, 0.f, 0.f};
#pragma unroll
            for (int kc = 0; kc < 8; kc++) {
                accA = __builtin_amdgcn_mfma_f32_16x16x32_bf16(fav[kc], fbv[0][kc], accA, 0, 0, 0);
                accB = __builtin_amdgcn_mfma_f32_16x16x32_bf16(fav[kc], fbv[1][kc], accB, 0, 0, 0);
            }
#pragma unroll
            for (int rr = 0; rr < 4; rr++) {
                BW2 pk; pk.b[0] = (__bf16)accA[rr]; pk.b[1] = (__bf16)accB[rr];
                *(unsigned int*)&zt[(q * 4 + rr) * 136 + w * 32 + 2 * n] = pk.u;
                ssum[0] += accA[rr]; ssq[0] = fmaf(accA[rr], accA[rr], ssq[0]);   // pad rows -> 0
                ssum[1] += accB[rr]; ssq[1] = fmaf(accB[rr], accB[rr], ssq[1]);
            }
            __syncthreads();   // B2: zt complete
            // ---- coalesced z2 store: 16 rows x 128 oc, one bf16x8 per thread ----
            {
                int row = tid >> 4, o = (tid & 15) * 8;
                int m = mt * 16 + row;
                if (m < 49) {
                    bf16x8 zv = *(const bf16x8*)&zt[row * 136 + o];
                    *(bf16x8*)&src[m * 128 + o] = zv;
                }
            }
        }
#pragma unroll
        for (int ntl = 0; ntl < 2; ntl++) {
            ssum[ntl] += __shfl_xor(ssum[ntl], 16); ssum[ntl] += __shfl_xor(ssum[ntl], 32);
            ssq[ntl]  += __shfl_xor(ssq[ntl], 16);  ssq[ntl]  += __shfl_xor(ssq[ntl], 32);
        }
        if (l < 16) {
#pragma unroll
            for (int ntl = 0; ntl < 2; ntl++) {
                int oc = w * 32 + 2 * l + ntl;
                part2[(long)oc * BSZ + b] = ssum[ntl];
                part2[(long)(128 + oc) * BSZ + b] = ssq[ntl];
            }
        }
    }
}

// ---------------- light epilogue: BN2 + ReLU + avgpool + FC from z2, 4 images/block ----------------
__global__ __launch_bounds__(256) void k_final(const __bf16* __restrict__ z2,
                                               const float* __restrict__ abc2,
                                               const float* __restrict__ wfc,
                                               const float* __restrict__ bfc,
                                               float* __restrict__ out) {
    __shared__ float sbn2[256];
    __shared__ float pp[16 * 128];
    __shared__ float pooled[128];
    __shared__ float fcred[80];
    const int tid = threadIdx.x;
    sbn2[tid] = abc2[tid];
    __syncthreads();
    const int g = tid & 15, c0 = g * 8, rg = tid >> 4;
    for (int img = 0; img < 4; img++) {
        const int b = blockIdx.x * 4 + img;
        const __bf16* src = z2 + (long)b * 12544;
        float acc[8];
#pragma unroll
        for (int q = 0; q < 8; q++) acc[q] = 0.f;
        for (int rr = rg; rr < 49; rr += 16) {
            bf16x8 v = *(const bf16x8*)&src[rr * 128 + c0];
#pragma unroll
            for (int q = 0; q < 8; q++) {
                float f = fmaxf((float)v[q] * sbn2[c0 + q] + sbn2[128 + c0 + q], 0.f);
                acc[q] += f;
            }
        }
        *(f32x4*)&pp[rg * 128 + c0]     = *(f32x4*)&acc[0];
        *(f32x4*)&pp[rg * 128 + c0 + 4] = *(f32x4*)&acc[4];
        __syncthreads();
        if (tid < 128) {
            float s = 0.f;
#pragma unroll
            for (int r = 0; r < 16; r++) s += pp[r * 128 + tid];
            pooled[tid] = s * (1.f / 49.f);
        }
        __syncthreads();
        if (tid < 80) {
            int o = tid >> 3, s = tid & 7;
            float a = 0.f;
#pragma unroll
            for (int j = 0; j < 16; j++) a = fmaf(pooled[s * 16 + j], wfc[o * 128 + s * 16 + j], a);
            fcred[tid] = a;
        }
        __syncthreads();
        if (tid < 10) {
            float a = bfc[tid];
#pragma unroll
            for (int s = 0; s < 8; s++) a += fcred[tid * 8 + s];
            out[(long)b * 10 + tid] = a;
        }
    }
}

extern "C" void kernel_launch(void* const* d_in, const int* in_sizes, int n_in,
                              void* d_out, int out_size, void* d_ws, size_t ws_size,
                              hipStream_t stream) {
    const float* x   = (const float*)d_in[0];
    const float* w0  = (const float*)d_in[1];
    const float* g0  = (const float*)d_in[3];
    const float* be0 = (const float*)d_in[4];
    const float* w1  = (const float*)d_in[5];
    const float* g1  = (const float*)d_in[7];
    const float* be1 = (const float*)d_in[8];
    const float* w2  = (const float*)d_in[9];
    const float* g2  = (const float*)d_in[11];
    const float* be2 = (const float*)d_in[12];
    const float* wfc = (const float*)d_in[13];
    const float* bfc = (const float*)d_in[14];
    float* out = (float*)d_out;

    float* ws    = (float*)d_ws;
    float* part0 = ws;                            // 1008*64 used; tail holds wcv
    __bf16* wcv  = (__bf16*)(part0 + 1008 * 64);  // 2048 bf16
    float* abc0  = part0 + 1024 * 64;             // (layout hole, compat)
    float* part1 = abc0 + 320;                    // 128*8192
    float* abc1  = part1 + 128 * BSZ;             // 128
    float* part2 = abc1 + 128;                    // 256*8192
    float* abc2  = part2 + 256 * BSZ;             // 256
    __bf16* w1b  = (__bf16*)(abc2 + 256);         // 8192
    __bf16* w2b  = w1b + 8192;                    // 32768
    __bf16* h1   = w2b + 32768;                   // 8192*12544 bf16 (~205 MB); z2 aliased per-image

    k_stats0<<<dim3(1008), dim3(256), 0, stream>>>(x, part0, w1, w2, w1b, w2b);
    k_fin0<<<dim3(1), dim3(256), 0, stream>>>(part0, w0, g0, be0, wcv);
    k_conv01<<<dim3(BSZ / 4), dim3(256), 0, stream>>>(x, wcv, w1b, h1, part1);
    k_redfin<<<dim3(64), dim3(256), 0, stream>>>(part1, g1, be1, abc1, 64, (float)(BSZ * 196));
    k_conv2s<<<dim3(BSZ / 4), dim3(256), 0, stream>>>(h1, w2b, abc1, part2);
    k_redfin<<<dim3(128), dim3(256), 0, stream>>>(part2, g2, be2, abc2, 128, (float)(BSZ * 49));
    k_final<<<dim3(BSZ / 4), dim3(256), 0, stream>>>(h1, abc2, wfc, bfc, out);
}

// Round 5
// 367.562 us; speedup vs baseline: 2.0359x; 1.0026x over previous
//
#include <hip/hip_runtime.h>
#include <hip/hip_bf16.h>

typedef __bf16 bf16x8 __attribute__((ext_vector_type(8)));
typedef float  f32x4  __attribute__((ext_vector_type(4)));

#define BSZ 8192

union BW2 { __bf16 b[2]; unsigned int u; };
union FR  { unsigned int u[4]; bf16x8 v; };

// ---------------- stats0 (9x9 second-moment) + weight prep merged ----------------
// prep: w1 -> w1b [64 oc][128 k], w2 -> w2b [128 oc][256 k], k = d*C + c
__global__ __launch_bounds__(256) void k_stats0(const float* __restrict__ x,
                                                float* __restrict__ part0,
                                                const float* __restrict__ w1,
                                                const float* __restrict__ w2,
                                                __bf16* __restrict__ w1b,
                                                __bf16* __restrict__ w2b) {
    __shared__ float sred[4 * 54];
    const int tid = threadIdx.x;
    {   // merged prep (first 128 blocks' thread-range)
        int t = blockIdx.x * 256 + tid;
        if (t < 8192) {           // w1: 64 oc x 128 k
            int oc = t >> 7, k = t & 127, c = k & 31, d = k >> 5;
            w1b[t] = (__bf16)w1[oc * 128 + c * 4 + d];
        }
        if (t < 32768) {          // w2: 128 oc x 256 k
            int oc = t >> 8, k = t & 255, c = k & 63, d = k >> 6;
            w2b[t] = (__bf16)w2[oc * 256 + c * 4 + d];
        }
    }
    float a[54];
#pragma unroll
    for (int i = 0; i < 54; i++) a[i] = 0.f;
    const int total = BSZ * 784;
    for (int p = blockIdx.x * 256 + tid; p < total; p += gridDim.x * 256) {
        int b = p / 784, pix = p - b * 784;
        int y = pix / 28, xx = pix - y * 28;
        const float* xb = x + (long)b * 784;
        float nv[9];
#pragma unroll
        for (int dy = 0; dy < 3; dy++) {
            int yy = y + dy - 1;
#pragma unroll
            for (int dx = 0; dx < 3; dx++) {
                int x2 = xx + dx - 1;
                nv[dy * 3 + dx] = (yy >= 0 && yy < 28 && x2 >= 0 && x2 < 28) ? xb[yy * 28 + x2] : 0.f;
            }
        }
        int idx = 0;
#pragma unroll
        for (int t2 = 0; t2 < 9; t2++) {
            float vt = nv[t2];
            a[45 + t2] += vt;
#pragma unroll
            for (int u = t2; u < 9; u++) { a[idx] += vt * nv[u]; idx++; }
        }
    }
#pragma unroll
    for (int i = 0; i < 54; i++) {
        float v = a[i];
        v += __shfl_xor(v, 1);  v += __shfl_xor(v, 2);  v += __shfl_xor(v, 4);
        v += __shfl_xor(v, 8);  v += __shfl_xor(v, 16); v += __shfl_xor(v, 32);
        a[i] = v;
    }
    const int l = tid & 63, w = tid >> 6;
    if (l == 0) {
#pragma unroll
        for (int i = 0; i < 54; i++) sred[w * 54 + i] = a[i];
    }
    __syncthreads();
    if (tid < 54)
        part0[blockIdx.x * 64 + tid] = sred[tid] + sred[54 + tid] + sred[108 + tid] + sred[162 + tid];
}

// finalize BN0; emit merged-pass conv0 B-fragments (bias folded into k-slots):
// B column n holds channels 2n+hh (hh = matrix 0/1). k = q*8 + e:
//   q<3 : e=2i+par (i<3): bf16(A*w[q*3+i]) for both parities (A supplies x_hi at e=2i, x_lo at 2i+1)
//         e=6: resid(q*3+0), e=7: resid(q*3+1)   (A supplies x_hi)
//   q==3: e=0: resid(2), e=1: resid(5), e=2: resid(8)  (A supplies x_hi of col-2 pixels)
//         e=4: bf16(bias), e=5: bias - bf16(bias)      (A supplies 1.0 at both)
__global__ void k_fin0(const float* __restrict__ part0, const float* __restrict__ w0,
                       const float* __restrict__ g0, const float* __restrict__ be0,
                       __bf16* __restrict__ wcv) {
    __shared__ float red[4 * 54];
    int t = threadIdx.x, c = t & 63, g = t >> 6;
    if (c < 54) {
        float acc = 0.f;
        for (int i = g; i < 1008; i += 4) acc += part0[i * 64 + c];
        red[g * 54 + c] = acc;
    }
    __syncthreads();
    if (t < 54) red[t] = red[t] + red[54 + t] + red[108 + t] + red[162 + t];
    __syncthreads();
    if (t < 32) {
        float wv[9];
#pragma unroll
        for (int tap = 0; tap < 9; tap++) wv[tap] = w0[t * 9 + tap];
        float sum = 0.f, sq = 0.f;
        int idx = 0;
#pragma unroll
        for (int ta = 0; ta < 9; ta++) {
            sum = fmaf(wv[ta], red[45 + ta], sum);
#pragma unroll
            for (int u = ta; u < 9; u++) {
                float coef = (u == ta) ? 1.f : 2.f;
                sq = fmaf(coef * wv[ta] * wv[u], red[idx], sq);
                idx++;
            }
        }
        float cnt = (float)BSZ * 784.f;
        float mean = sum / cnt;
        float var = sq / cnt - mean * mean;
        float A = g0[t] * rsqrtf(var + 1e-5f);
        float bias = be0[t] - mean * A;
        __bf16 bhi = (__bf16)bias;
        float blo = bias - (float)bhi;
        int nn = t >> 1, hh = t & 1;
#pragma unroll
        for (int qq = 0; qq < 4; qq++) {
#pragma unroll
            for (int e = 0; e < 8; e++) {
                float v = 0.f;
                if (qq < 3) {
                    if (e < 6) {
                        int i = e >> 1;
                        v = (float)((__bf16)(A * wv[qq * 3 + i]));
                    } else if (e == 6) {
                        float wf = A * wv[qq * 3 + 0]; v = wf - (float)((__bf16)wf);
                    } else {
                        float wf = A * wv[qq * 3 + 1]; v = wf - (float)((__bf16)wf);
                    }
                } else {
                    if (e == 0)      { float wf = A * wv[2]; v = wf - (float)((__bf16)wf); }
                    else if (e == 1) { float wf = A * wv[5]; v = wf - (float)((__bf16)wf); }
                    else if (e == 2) { float wf = A * wv[8]; v = wf - (float)((__bf16)wf); }
                    else if (e == 4) v = (float)bhi;
                    else if (e == 5) v = blo;
                }
                wcv[hh * 512 + qq * 128 + nn * 8 + e] = (__bf16)v;
            }
        }
    }
}

// ---------------- shared conv0 core pieces ----------------
struct C0S {
    bf16x8 bwM0, bwM1;
    int q, n;
    int Koff, off1, off2;
    bool q3;
};

__device__ inline void c0_init(C0S& S, const __bf16* __restrict__ wcv, int l) {
    S.q = l >> 4; S.n = l & 15; S.q3 = (S.q == 3);
    S.bwM0 = *(const bf16x8*)&wcv[S.q * 128 + S.n * 8];
    S.bwM1 = *(const bf16x8*)&wcv[512 + S.q * 128 + S.n * 8];
    S.Koff = S.q3 ? 2 : S.q * 30;
    S.off1 = S.q3 ? 30 : 1;
    S.off2 = S.q3 ? 60 : 2;
}

// produce one conv1 A-tile (16 positions x 128 k) into sAtw (stride 136), merged-pass conv0.
__device__ inline void c0_produce(const C0S& S, const unsigned* __restrict__ xs2w,
                                  __bf16* sAtw, int my, int mx, bool zpad) {
    const int b00 = 2 * my * 30 + 2 * mx + S.Koff;
#pragma unroll
    for (int t = 0; t < 4; t++) {
        const int d1 = t >> 1, d0 = t & 1;
        const unsigned* p = xs2w + b00 + d1 * 30 + d0;
        unsigned v0 = p[0], v1 = p[S.off1], v2 = p[S.off2];
        unsigned pm = __builtin_amdgcn_perm(v1, v0, 0x05040100u);   // (hi(v0), hi(v1))
        FR A;
        A.u[0] = S.q3 ? pm : v0;
        A.u[1] = S.q3 ? (v2 & 0xffffu) : v1;
        A.u[2] = S.q3 ? 0x3F803F80u : v2;     // q3: (1.0, 1.0) for bias hi/lo slots
        A.u[3] = S.q3 ? 0u : pm;
        f32x4 z = {0.f, 0.f, 0.f, 0.f};
        f32x4 ac0 = __builtin_amdgcn_mfma_f32_16x16x32_bf16(A.v, S.bwM0, z, 0, 0, 0);
        f32x4 ac1 = __builtin_amdgcn_mfma_f32_16x16x32_bf16(A.v, S.bwM1, z, 0, 0, 0);
#pragma unroll
        for (int r = 0; r < 4; r++) {
            float a0 = fmaxf(ac0[r], 0.f), a1 = fmaxf(ac1[r], 0.f);
            if (zpad) { a0 = 0.f; a1 = 0.f; }
            BW2 pk; pk.b[0] = (__bf16)a0; pk.b[1] = (__bf16)a1;
            *(unsigned*)&sAtw[(S.q * 4 + r) * 136 + t * 32 + 2 * S.n] = pk.u;
        }
    }
}

__device__ inline void stage_img(unsigned* xs2w, const float* __restrict__ x,
                                 long b, int t0, int stride) {
    for (int jj = t0; jj < 784; jj += stride) {
        int yy = jj / 28, xx2 = jj - yy * 28;
        float f = x[b * 784 + jj];
        __bf16 hi = (__bf16)f;
        __bf16 lo = (__bf16)(f - (float)hi);
        BW2 pk; pk.b[0] = hi; pk.b[1] = lo;
        xs2w[(yy + 1) * 30 + xx2 + 1] = pk.u;
    }
}

// ---------------- conv0 (merged-pass MFMA) + conv1 (MFMA) -> h1 + BN1 stats ----------------
// 4 independent waves per block, 1 wave = 1 image, barrier-free (per-wave LDS, in-order DS pipe).
// oc remap 4n+g => per-row 8B packed h1 stores.
__global__ __launch_bounds__(256, 4) void k_conv01(const float* __restrict__ x,
                                                   const __bf16* __restrict__ wcv,
                                                   const __bf16* __restrict__ w1b,
                                                   __bf16* __restrict__ h1,
                                                   float* __restrict__ part1) {
    __shared__ unsigned xs2a[4][900];
    __shared__ __attribute__((aligned(16))) __bf16 sAta[4][16 * 136];
    const int tid = threadIdx.x, w = tid >> 6, l = tid & 63;
    const int q = l >> 4, n = l & 15;
    unsigned* xs2w = xs2a[w];
    __bf16* sAtw = sAta[w];
    C0S S0; c0_init(S0, wcv, l);
    bf16x8 fbv[4][4];
#pragma unroll
    for (int g = 0; g < 4; g++)
#pragma unroll
        for (int kc = 0; kc < 4; kc++)
            fbv[g][kc] = *(const bf16x8*)&w1b[(4 * n + g) * 128 + kc * 32 + q * 8];
    const long b = (long)blockIdx.x * 4 + w;
    for (int i = l; i < 900; i += 64) xs2w[i] = 0u;
    stage_img(xs2w, x, b, l, 64);
    float ssum[4] = {0.f, 0.f, 0.f, 0.f}, ssq[4] = {0.f, 0.f, 0.f, 0.f};
    __bf16* hb = h1 + b * 12544;
    for (int mt = 0; mt < 13; mt++) {
        const bool last = (mt == 12);
        int mv = (last && n >= 4) ? 195 : mt * 16 + n;
        int my = mv / 14, mx = mv - my * 14;
        c0_produce(S0, xs2w, sAtw, my, mx, last && (q != 0));
        const __bf16* sa = &sAtw[n * 136 + q * 8];
        bf16x8 fav[4];
#pragma unroll
        for (int kc = 0; kc < 4; kc++) fav[kc] = *(const bf16x8*)&sa[kc * 32];
        f32x4 a[4];
        __builtin_amdgcn_s_setprio(1);
#pragma unroll
        for (int g = 0; g < 4; g++) {
            f32x4 acc = {0.f, 0.f, 0.f, 0.f};
#pragma unroll
            for (int kc = 0; kc < 4; kc++)
                acc = __builtin_amdgcn_mfma_f32_16x16x32_bf16(fav[kc], fbv[g][kc], acc, 0, 0, 0);
            a[g] = acc;
        }
        __builtin_amdgcn_s_setprio(0);
#pragma unroll
        for (int g = 0; g < 4; g++)
#pragma unroll
            for (int r = 0; r < 4; r++) {
                ssum[g] += a[g][r];                  // pad rows produce exact 0
                ssq[g] = fmaf(a[g][r], a[g][r], ssq[g]);
            }
        if ((mt < 12) | (q == 0)) {
#pragma unroll
            for (int r = 0; r < 4; r++) {
                BW2 p0, p1;
                p0.b[0] = (__bf16)a[0][r]; p0.b[1] = (__bf16)a[1][r];
                p1.b[0] = (__bf16)a[2][r]; p1.b[1] = (__bf16)a[3][r];
                uint2 u; u.x = p0.u; u.y = p1.u;
                *(uint2*)&hb[(mt * 16 + q * 4 + r) * 64 + 4 * n] = u;
            }
        }
    }
#pragma unroll
    for (int g = 0; g < 4; g++) {
        ssum[g] += __shfl_xor(ssum[g], 16); ssum[g] += __shfl_xor(ssum[g], 32);
        ssq[g]  += __shfl_xor(ssq[g], 16);  ssq[g]  += __shfl_xor(ssq[g], 32);
    }
    if (l < 16) {
#pragma unroll
        for (int g = 0; g < 4; g++) {
            part1[(long)(4 * l + g) * BSZ + b] = ssum[g];
            part1[(long)(64 + 4 * l + g) * BSZ + b] = ssq[g];
        }
    }
}

// ---------------- fused per-channel column reduce + BN finalize ----------------
__global__ __launch_bounds__(256) void k_redfin(const float* __restrict__ part,
                                                const float* __restrict__ g,
                                                const float* __restrict__ be,
                                                float* __restrict__ abc,
                                                int C, float cnt) {
    __shared__ float s1[256], s2[256];
    const int c = blockIdx.x, tid = threadIdx.x;
    float a = 0.f, bq = 0.f;
    const float* p1 = part + (long)c * BSZ;
    const float* p2 = part + (long)(C + c) * BSZ;
    for (int i = tid; i < BSZ; i += 256) { a += p1[i]; bq += p2[i]; }
    s1[tid] = a; s2[tid] = bq;
    __syncthreads();
    for (int s = 128; s > 0; s >>= 1) {
        if (tid < s) { s1[tid] += s1[tid + s]; s2[tid] += s2[tid + s]; }
        __syncthreads();
    }
    if (tid == 0) {
        float mean = s1[0] / cnt;
        float var = s2[0] / cnt - mean * mean;
        float A = g[c] * rsqrtf(var + 1e-5f);
        abc[c] = A;
        abc[C + c] = be[c] - mean * A;
    }
}

// ---------------- conv2 MFMA (BN1+ReLU on load), pipelined, 4 images/block ----------------
// One barrier per tile (raw s_barrier + lgkmcnt, vmcnt prefetch stays in flight).
// h1 loads for tile li+1 issued before the barrier of tile li (T14 async-stage split).
// z2 stores go DIRECT from accumulators (oc = w*32+2n+ntl pair-packing -> dword stores,
// 16 lanes = 128B contiguous). Alias safety (prefetch before store): tile mt+1 reads
// h1 elems >= 3840/7680/11520; z2 writes of tiles <= mt stay < (mt+1)*2048 -> disjoint.
__global__ __launch_bounds__(256) void k_conv2s(__bf16* __restrict__ h1,
                                                const __bf16* __restrict__ w2b,
                                                const float* __restrict__ abc1,
                                                float* __restrict__ part2) {
    __shared__ __attribute__((aligned(16))) __bf16 sAt[2][16 * 264];
    __shared__ float sbn1[128];
    const int tid = threadIdx.x;
    if (tid < 128) sbn1[tid] = abc1[tid];
    const int w = tid >> 6, l = tid & 63, q = l >> 4, n = l & 15;
    bf16x8 fbv[2][8];
#pragma unroll
    for (int ntl = 0; ntl < 2; ntl++) {
        int oc = w * 32 + 2 * n + ntl;
#pragma unroll
        for (int kc = 0; kc < 8; kc++)
            fbv[ntl][kc] = *(const bf16x8*)&w2b[oc * 256 + kc * 32 + q * 8];
    }
    // produce-chunk geometry: chunk k (k=0,1): rl = k*8 + (tid>>5), o = (tid&31)*8
    const int rlA = tid >> 5, rlB = 8 + (tid >> 5), oo = (tid & 31) * 8;
    const int dA = oo >> 6, cA = oo & 63;        // same for both chunks

    auto issue = [&](int li, bf16x8& A0, bf16x8& A1) {
        const int img = li >> 2, mt = li & 3;
        const __bf16* src = h1 + ((long)blockIdx.x * 4 + img) * 12544;
        int r0 = mt * 16 + rlA;
        if (r0 < 49) {
            int py = r0 / 7, px = r0 - py * 7;
            int msrc = (2 * py + (dA >> 1)) * 14 + 2 * px + (dA & 1);
            A0 = *(const bf16x8*)&src[msrc * 64 + cA];
        }
        int r1 = mt * 16 + rlB;
        if (r1 < 49) {
            int py = r1 / 7, px = r1 - py * 7;
            int msrc = (2 * py + (dA >> 1)) * 14 + 2 * px + (dA & 1);
            A1 = *(const bf16x8*)&src[msrc * 64 + cA];
        }
    };
    auto put = [&](int li, bf16x8 A0, bf16x8 A1) {
        const int mt = li & 3;
        __bf16* sb = sAt[li & 1];
        bf16x8 wv;
        if (mt * 16 + rlA < 49) {
#pragma unroll
            for (int j = 0; j < 8; j++)
                wv[j] = (__bf16)fmaxf((float)A0[j] * sbn1[cA + j] + sbn1[64 + cA + j], 0.f);
        } else {
#pragma unroll
            for (int j = 0; j < 8; j++) wv[j] = (__bf16)0.0f;
        }
        *(bf16x8*)&sb[rlA * 264 + oo] = wv;
        if (mt * 16 + rlB < 49) {
#pragma unroll
            for (int j = 0; j < 8; j++)
                wv[j] = (__bf16)fmaxf((float)A1[j] * sbn1[cA + j] + sbn1[64 + cA + j], 0.f);
        } else {
#pragma unroll
            for (int j = 0; j < 8; j++) wv[j] = (__bf16)0.0f;
        }
        *(bf16x8*)&sb[rlB * 264 + oo] = wv;
    };

    bf16x8 cur0 = {}, cur1 = {}, nxt0 = {}, nxt1 = {};
    issue(0, cur0, cur1);
    __syncthreads();   // sbn1 ready
    float ssum[2] = {0.f, 0.f}, ssq[2] = {0.f, 0.f};
    for (int li = 0; li < 16; li++) {
        const int img = li >> 2, mt = li & 3;
        put(li, cur0, cur1);
        if (li < 15) issue(li + 1, nxt0, nxt1);
        __builtin_amdgcn_sched_barrier(0);
        asm volatile("s_waitcnt lgkmcnt(0)" ::: "memory");
        __builtin_amdgcn_s_barrier();
        __builtin_amdgcn_sched_barrier(0);
        // ---- consume tile: MFMA -> direct z2 stores + f32 stats ----
        const __bf16* sb = sAt[li & 1];
        bf16x8 fav[8];
#pragma unroll
        for (int kc = 0; kc < 8; kc++)
            fav[kc] = *(const bf16x8*)&sb[n * 264 + kc * 32 + q * 8];
        f32x4 accA = {0.f, 0.f, 0.f, 0.f}, accB = {0.f, 0.f, 0.f, 0.f};
        __builtin_amdgcn_s_setprio(1);
#pragma unroll
        for (int kc = 0; kc < 8; kc++) {
            accA = __builtin_amdgcn_mfma_f32_16x16x32_bf16(fav[kc], fbv[0][kc], accA, 0, 0, 0);
            accB = __builtin_amdgcn_mfma_f32_16x16x32_bf16(fav[kc], fbv[1][kc], accB, 0, 0, 0);
        }
        __builtin_amdgcn_s_setprio(0);
        __bf16* src = h1 + ((long)blockIdx.x * 4 + img) * 12544;
#pragma unroll
        for (int rr = 0; rr < 4; rr++) {
            int m = mt * 16 + q * 4 + rr;
            BW2 pk; pk.b[0] = (__bf16)accA[rr]; pk.b[1] = (__bf16)accB[rr];
            if (m < 49) *(unsigned int*)&src[m * 128 + w * 32 + 2 * n] = pk.u;
            ssum[0] += accA[rr]; ssq[0] = fmaf(accA[rr], accA[rr], ssq[0]);   // pad rows -> 0
            ssum[1] += accB[rr]; ssq[1] = fmaf(accB[rr], accB[rr], ssq[1]);
        }
        cur0 = nxt0; cur1 = nxt1;
        if (mt == 3) {   // finalize this image's stats
            const long b = (long)blockIdx.x * 4 + img;
#pragma unroll
            for (int ntl = 0; ntl < 2; ntl++) {
                ssum[ntl] += __shfl_xor(ssum[ntl], 16); ssum[ntl] += __shfl_xor(ssum[ntl], 32);
                ssq[ntl]  += __shfl_xor(ssq[ntl], 16);  ssq[ntl]  += __shfl_xor(ssq[ntl], 32);
            }
            if (l < 16) {
#pragma unroll
                for (int ntl = 0; ntl < 2; ntl++) {
                    int oc = w * 32 + 2 * l + ntl;
                    part2[(long)oc * BSZ + b] = ssum[ntl];
                    part2[(long)(128 + oc) * BSZ + b] = ssq[ntl];
                }
            }
            ssum[0] = ssum[1] = ssq[0] = ssq[1] = 0.f;
        }
    }
}

// ---------------- epilogue: BN2+ReLU+avgpool+FC, 1 wave = 1 image, barrier-free ----------------
__global__ __launch_bounds__(256) void k_final(const __bf16* __restrict__ z2,
                                               const float* __restrict__ abc2,
                                               const float* __restrict__ wfc,
                                               const float* __restrict__ bfc,
                                               float* __restrict__ out) {
    const int tid = threadIdx.x, w = tid >> 6, l = tid & 63;
    const int q = l >> 4, g = l & 15;
    const long b = (long)blockIdx.x * 4 + w;
    const __bf16* src = z2 + b * 12544;
    f32x4 a2lo = *(const f32x4*)&abc2[g * 8];
    f32x4 a2hi = *(const f32x4*)&abc2[g * 8 + 4];
    f32x4 b2lo = *(const f32x4*)&abc2[128 + g * 8];
    f32x4 b2hi = *(const f32x4*)&abc2[128 + g * 8 + 4];
    float acc[8];
#pragma unroll
    for (int j = 0; j < 8; j++) acc[j] = 0.f;
    for (int r = q; r < 49; r += 4) {
        bf16x8 v = *(const bf16x8*)&src[r * 128 + g * 8];
#pragma unroll
        for (int j = 0; j < 4; j++) {
            acc[j]     += fmaxf((float)v[j]     * a2lo[j] + b2lo[j], 0.f);
            acc[4 + j] += fmaxf((float)v[4 + j] * a2hi[j] + b2hi[j], 0.f);
        }
    }
#pragma unroll
    for (int j = 0; j < 8; j++) {
        acc[j] += __shfl_xor(acc[j], 16);
        acc[j] += __shfl_xor(acc[j], 32);
        acc[j] *= (1.f / 49.f);
    }
    float p[10];
#pragma unroll
    for (int o = 0; o < 10; o++) {
        f32x4 w0 = *(const f32x4*)&wfc[o * 128 + g * 8];
        f32x4 w1 = *(const f32x4*)&wfc[o * 128 + g * 8 + 4];
        float s = 0.f;
#pragma unroll
        for (int j = 0; j < 4; j++) {
            s = fmaf(acc[j], w0[j], s);
            s = fmaf(acc[4 + j], w1[j], s);
        }
        p[o] = s;
    }
#pragma unroll
    for (int o = 0; o < 10; o++) {
        p[o] += __shfl_xor(p[o], 1); p[o] += __shfl_xor(p[o], 2);
        p[o] += __shfl_xor(p[o], 4); p[o] += __shfl_xor(p[o], 8);
    }
    if (l == 0) {
#pragma unroll
        for (int o = 0; o < 10; o++) out[b * 10 + o] = p[o] + bfc[o];
    }
}

extern "C" void kernel_launch(void* const* d_in, const int* in_sizes, int n_in,
                              void* d_out, int out_size, void* d_ws, size_t ws_size,
                              hipStream_t stream) {
    const float* x   = (const float*)d_in[0];
    const float* w0  = (const float*)d_in[1];
    const float* g0  = (const float*)d_in[3];
    const float* be0 = (const float*)d_in[4];
    const float* w1  = (const float*)d_in[5];
    const float* g1  = (const float*)d_in[7];
    const float* be1 = (const float*)d_in[8];
    const float* w2  = (const float*)d_in[9];
    const float* g2  = (const float*)d_in[11];
    const float* be2 = (const float*)d_in[12];
    const float* wfc = (const float*)d_in[13];
    const float* bfc = (const float*)d_in[14];
    float* out = (float*)d_out;

    float* ws    = (float*)d_ws;
    float* part0 = ws;                            // 1008*64 used; tail holds wcv
    __bf16* wcv  = (__bf16*)(part0 + 1008 * 64);  // 2048 bf16
    float* abc0  = part0 + 1024 * 64;             // (layout hole, compat)
    float* part1 = abc0 + 320;                    // 128*8192
    float* abc1  = part1 + 128 * BSZ;             // 128
    float* part2 = abc1 + 128;                    // 256*8192
    float* abc2  = part2 + 256 * BSZ;             // 256
    __bf16* w1b  = (__bf16*)(abc2 + 256);         // 8192
    __bf16* w2b  = w1b + 8192;                    // 32768
    __bf16* h1   = w2b + 32768;                   // 8192*12544 bf16 (~205 MB); z2 aliased per-image

    k_stats0<<<dim3(1008), dim3(256), 0, stream>>>(x, part0, w1, w2, w1b, w2b);
    k_fin0<<<dim3(1), dim3(256), 0, stream>>>(part0, w0, g0, be0, wcv);
    k_conv01<<<dim3(BSZ / 4), dim3(256), 0, stream>>>(x, wcv, w1b, h1, part1);
    k_redfin<<<dim3(64), dim3(256), 0, stream>>>(part1, g1, be1, abc1, 64, (float)(BSZ * 196));
    k_conv2s<<<dim3(BSZ / 4), dim3(256), 0, stream>>>(h1, w2b, abc1, part2);
    k_redfin<<<dim3(128), dim3(256), 0, stream>>>(part2, g2, be2, abc2, 128, (float)(BSZ * 49));
    k_final<<<dim3(BSZ / 4), dim3(256), 0, stream>>>(h1, abc2, wfc, bfc, out);
}